// Round 7
// baseline (3090.633 us; speedup 1.0000x reference)
//
#include <hip/hip_runtime.h>
#include <math.h>

#define BB 16
#define LL 128
#define HH 1024
#define EE 512
#define VV 32000
#define G3 3072
#define NBLK 256

__device__ __forceinline__ float sigmoidf_(float x){ return 1.0f/(1.0f+expf(-x)); }

__global__ void k_rowidx(const int* __restrict__ inp, int* __restrict__ idx){
  int r = blockIdx.x*256 + threadIdx.x;
  if (r < 2048){ int l = r >> 4, b = r & 15; idx[r] = inp[b*LL + l]; }
}

template<int ACT, int KK>
__global__ __launch_bounds__(256) void k_gemm(const float* __restrict__ A, const int* __restrict__ rowidx,
                       const float* __restrict__ Bm, const float* __restrict__ bias,
                       float* __restrict__ C, int N){
  constexpr int KS = (KK==512)?9:10;
  __shared__ float As[32*KK];
  const int tid = threadIdx.x;
  const int r0 = blockIdx.x*32;
  const int c  = blockIdx.y*512 + (tid<<1);
  for (int i = tid; i < 32*KK; i += 256){
    int rr = i >> KS;
    int row = r0 + rr;
    int arow = rowidx ? rowidx[row] : row;
    int kk = i - (rr<<KS);
    As[i] = A[(size_t)arow*KK + kk];
  }
  __syncthreads();
  float2 acc[32];
  #pragma unroll
  for (int r=0;r<32;r++){ acc[r].x=0.f; acc[r].y=0.f; }
  for (int k=0;k<KK;k++){
    const float2 w = *(const float2*)(Bm + (size_t)k*N + c);
    #pragma unroll
    for (int r=0;r<32;r++){
      float a = As[(r<<KS)+k];
      acc[r].x = fmaf(a,w.x,acc[r].x);
      acc[r].y = fmaf(a,w.y,acc[r].y);
    }
  }
  const float2 bv = *(const float2*)(bias + c);
  #pragma unroll
  for (int r=0;r<32;r++){
    float x = acc[r].x + bv.x, y = acc[r].y + bv.y;
    if (ACT==1){ x = tanhf(x); y = tanhf(y); }
    *(float2*)(C + (size_t)(r0+r)*N + c) = make_float2(x,y);
  }
}

// Fused persistent kernel: both GRU layers + gx1 GEMV, pipelined.
// Round t: layer0 step t (t<128), gx1[t-1]=h0[t-1]@Wih1 and layer1 step t-1
// (t>=1). 256 blocks x 4 cols; LDS = Whh0|Whh1|Wih1 col-slices (144 KB).
// gx0 (constant over steps) computed in prologue via w0l as scratch.
__global__ __launch_bounds__(256,1) void k_chains(
    const float* enclast, float* H0all, float* H1all,
    const float* __restrict__ Whh0, const float* __restrict__ Whh1,
    const float* __restrict__ Wih0, const float* __restrict__ Wih1,
    const float* __restrict__ emb,
    const float* __restrict__ bih0, const float* __restrict__ bhh0,
    const float* __restrict__ bhh1, const float* __restrict__ bih1,
    int* flags, int* go)
{
  __shared__ float w0l[12][1024];
  __shared__ float w1l[12][1024];
  __shared__ float wil[12][1024];
  const int tid = threadIdx.x;
  const int kc = tid & 63, bc = tid >> 6;
  const int jb = blockIdx.x << 2;
  const int b0 = bc << 2;
  const int jl = kc & 3, bi_p = kc >> 2;
  const int jp = jb + jl, bp = b0 + bi_p;

  // ---- prologue 1: gx0 for this block's 12 gate-cols (w0l as scratch) ----
  float g0r=0.f, g0z=0.f, g0n=0.f;
  {
    for (int i = tid; i < 1536; i += 256){
      int g = i >> 9, k = i & 511;
      float4 a = *(const float4*)(Wih0 + (size_t)k*G3 + g*1024 + jb);
      w0l[g*4+0][k]=a.x; w0l[g*4+1][k]=a.y; w0l[g*4+2][k]=a.z; w0l[g*4+3][k]=a.w;
    }
    __syncthreads();
    const float* e1 = emb + EE;   // SOS row (index 1)
    float ag[12];
    #pragma unroll
    for (int c=0;c<12;c++) ag[c]=0.f;
    #pragma unroll
    for (int q=0;q<2;q++){
      float4 e = *(const float4*)(e1 + q*256 + (kc<<2));
      #pragma unroll
      for (int c=0;c<12;c++){
        const float4 w = *(const float4*)(&w0l[c][q*256 + (kc<<2)]);
        float v = ag[c];
        v = fmaf(w.x,e.x,v); v = fmaf(w.y,e.y,v);
        v = fmaf(w.z,e.z,v); v = fmaf(w.w,e.w,v);
        ag[c]=v;
      }
    }
    #pragma unroll
    for (int c=0;c<12;c++){
      float v = ag[c];
      v += __shfl_xor(v,1,64); v += __shfl_xor(v,2,64); v += __shfl_xor(v,4,64);
      v += __shfl_xor(v,8,64); v += __shfl_xor(v,16,64); v += __shfl_xor(v,32,64);
      ag[c]=v;
    }
    if (kc < 16){
      #pragma unroll
      for (int c=0;c<4;c++){
        bool sel = (jl==c);
        g0r = sel ? ag[c]   : g0r;
        g0z = sel ? ag[4+c] : g0z;
        g0n = sel ? ag[8+c] : g0n;
      }
      g0r += bih0[jp]; g0z += bih0[1024+jp]; g0n += bih0[2048+jp];
    }
    __syncthreads();   // done with scratch
  }

  // ---- prologue 2: stage the three weight slices ----
  for (int i = tid; i < 3072; i += 256){
    int g = i >> 10, k = i & 1023;
    float4 a = *(const float4*)(Whh0 + (size_t)k*G3 + g*1024 + jb);
    w0l[g*4+0][k]=a.x; w0l[g*4+1][k]=a.y; w0l[g*4+2][k]=a.z; w0l[g*4+3][k]=a.w;
    float4 b = *(const float4*)(Whh1 + (size_t)k*G3 + g*1024 + jb);
    w1l[g*4+0][k]=b.x; w1l[g*4+1][k]=b.y; w1l[g*4+2][k]=b.z; w1l[g*4+3][k]=b.w;
    float4 c = *(const float4*)(Wih1 + (size_t)k*G3 + g*1024 + jb);
    wil[g*4+0][k]=c.x; wil[g*4+1][k]=c.y; wil[g*4+2][k]=c.z; wil[g*4+3][k]=c.w;
  }
  float b0r_=0.f,b0z_=0.f,b0n_=0.f,b1r_=0.f,b1z_=0.f,b1n_=0.f,bir_=0.f,biz_=0.f,bin_=0.f;
  if (kc < 16){
    b0r_ = bhh0[jp]; b0z_ = bhh0[1024+jp]; b0n_ = bhh0[2048+jp];
    b1r_ = bhh1[jp]; b1z_ = bhh1[1024+jp]; b1n_ = bhh1[2048+jp];
    bir_ = bih1[jp]; biz_ = bih1[1024+jp]; bin_ = bih1[2048+jp];
  }
  __syncthreads();

  for (int t = 0; t <= LL; ++t){
    const float* hp0 = (t==0) ? enclast : (H0all + (size_t)(t-1)*(BB*HH));
    const float* hp1 = (t<=1) ? enclast : (H1all + (size_t)(t-2)*(BB*HH));

    // ---- phase A: acc0 = h0prev@Whh0, accg = h0prev@Wih1 ----
    float acc0[12][4], accg[12][4];
    #pragma unroll
    for (int c=0;c<12;c++)
      #pragma unroll
      for (int bi=0;bi<4;bi++){ acc0[c][bi]=0.f; accg[c][bi]=0.f; }

    #pragma unroll
    for (int q=0;q<4;q++){
      float4 h[4];
      #pragma unroll
      for (int bi=0;bi<4;bi++)
        h[bi] = *(const float4*)(hp0 + (size_t)(b0+bi)*HH + q*256 + (kc<<2));
      #pragma unroll
      for (int c=0;c<12;c++){
        const float4 wa = *(const float4*)(&w0l[c][q*256 + (kc<<2)]);
        const float4 wg = *(const float4*)(&wil[c][q*256 + (kc<<2)]);
        #pragma unroll
        for (int bi=0;bi<4;bi++){
          float v0 = acc0[c][bi], vg = accg[c][bi];
          v0 = fmaf(wa.x,h[bi].x,v0); v0 = fmaf(wa.y,h[bi].y,v0);
          v0 = fmaf(wa.z,h[bi].z,v0); v0 = fmaf(wa.w,h[bi].w,v0);
          vg = fmaf(wg.x,h[bi].x,vg); vg = fmaf(wg.y,h[bi].y,vg);
          vg = fmaf(wg.z,h[bi].z,vg); vg = fmaf(wg.w,h[bi].w,vg);
          acc0[c][bi]=v0; accg[c][bi]=vg;
        }
      }
    }
    #pragma unroll
    for (int c=0;c<12;c++)
      #pragma unroll
      for (int bi=0;bi<4;bi++){
        float v = acc0[c][bi];
        v += __shfl_xor(v,1,64); v += __shfl_xor(v,2,64); v += __shfl_xor(v,4,64);
        v += __shfl_xor(v,8,64); v += __shfl_xor(v,16,64); v += __shfl_xor(v,32,64);
        acc0[c][bi]=v;
        float w = accg[c][bi];
        w += __shfl_xor(w,1,64); w += __shfl_xor(w,2,64); w += __shfl_xor(w,4,64);
        w += __shfl_xor(w,8,64); w += __shfl_xor(w,16,64); w += __shfl_xor(w,32,64);
        accg[c][bi]=w;
      }

    if (t < LL && kc < 16){
      float ghr=0.f, ghz=0.f, ghn=0.f;
      #pragma unroll
      for (int c=0;c<4;c++)
        #pragma unroll
        for (int bi=0;bi<4;bi++){
          bool sel = (jl==c) & (bi_p==bi);
          ghr = sel ? acc0[c][bi]   : ghr;
          ghz = sel ? acc0[4+c][bi] : ghz;
          ghn = sel ? acc0[8+c][bi] : ghn;
        }
      float r = sigmoidf_(g0r + ghr + b0r_);
      float z = sigmoidf_(g0z + ghz + b0z_);
      float n = tanhf    (g0n + r*(ghn + b0n_));
      float hprev = hp0[(size_t)bp*HH + jp];
      float hnew  = (1.f-z)*n + z*hprev;
      __hip_atomic_store((int*)&H0all[(size_t)t*(BB*HH) + (size_t)bp*HH + jp],
                         __float_as_int(hnew),
                         __ATOMIC_RELAXED, __HIP_MEMORY_SCOPE_AGENT);
    }

    // ---- phase B: acc1 = h1prev@Whh1; layer1 gates with accg ----
    float acc1[12][4];
    #pragma unroll
    for (int c=0;c<12;c++)
      #pragma unroll
      for (int bi=0;bi<4;bi++) acc1[c][bi]=0.f;

    #pragma unroll
    for (int q=0;q<4;q++){
      float4 h[4];
      #pragma unroll
      for (int bi=0;bi<4;bi++)
        h[bi] = *(const float4*)(hp1 + (size_t)(b0+bi)*HH + q*256 + (kc<<2));
      #pragma unroll
      for (int c=0;c<12;c++){
        const float4 w = *(const float4*)(&w1l[c][q*256 + (kc<<2)]);
        #pragma unroll
        for (int bi=0;bi<4;bi++){
          float v = acc1[c][bi];
          v = fmaf(w.x,h[bi].x,v); v = fmaf(w.y,h[bi].y,v);
          v = fmaf(w.z,h[bi].z,v); v = fmaf(w.w,h[bi].w,v);
          acc1[c][bi]=v;
        }
      }
    }
    #pragma unroll
    for (int c=0;c<12;c++)
      #pragma unroll
      for (int bi=0;bi<4;bi++){
        float v = acc1[c][bi];
        v += __shfl_xor(v,1,64); v += __shfl_xor(v,2,64); v += __shfl_xor(v,4,64);
        v += __shfl_xor(v,8,64); v += __shfl_xor(v,16,64); v += __shfl_xor(v,32,64);
        acc1[c][bi]=v;
      }

    if (t >= 1 && kc < 16){
      float ghr=0.f, ghz=0.f, ghn=0.f, gxr=0.f, gxz=0.f, gxn=0.f;
      #pragma unroll
      for (int c=0;c<4;c++)
        #pragma unroll
        for (int bi=0;bi<4;bi++){
          bool sel = (jl==c) & (bi_p==bi);
          ghr = sel ? acc1[c][bi]   : ghr;
          ghz = sel ? acc1[4+c][bi] : ghz;
          ghn = sel ? acc1[8+c][bi] : ghn;
          gxr = sel ? accg[c][bi]   : gxr;
          gxz = sel ? accg[4+c][bi] : gxz;
          gxn = sel ? accg[8+c][bi] : gxn;
        }
      float r = sigmoidf_(gxr + bir_ + ghr + b1r_);
      float z = sigmoidf_(gxz + biz_ + ghz + b1z_);
      float n = tanhf    (gxn + bin_ + r*(ghn + b1n_));
      float hprev = hp1[(size_t)bp*HH + jp];
      float hnew  = (1.f-z)*n + z*hprev;
      __hip_atomic_store((int*)&H1all[(size_t)(t-1)*(BB*HH) + (size_t)bp*HH + jp],
                         __float_as_int(hnew),
                         __ATOMIC_RELAXED, __HIP_MEMORY_SCOPE_AGENT);
    }

    // ---- handshake (skip after last round) ----
    if (t < LL){
      const int val = t + 1;
      asm volatile("s_waitcnt vmcnt(0)" ::: "memory");
      __syncthreads();
      if (tid == 0)
        __hip_atomic_store(&flags[(int)blockIdx.x*32], val,
                           __ATOMIC_RELAXED, __HIP_MEMORY_SCOPE_AGENT);
      if (blockIdx.x == 0){
        while (__hip_atomic_load(&flags[tid*32], __ATOMIC_RELAXED,
                                 __HIP_MEMORY_SCOPE_AGENT) < val)
          __builtin_amdgcn_s_sleep(1);
        __syncthreads();
        if (tid == 0)
          __hip_atomic_store(go, val, __ATOMIC_RELAXED, __HIP_MEMORY_SCOPE_AGENT);
      } else {
        if (tid == 0){
          while (__hip_atomic_load(go, __ATOMIC_RELAXED,
                                   __HIP_MEMORY_SCOPE_AGENT) < val)
            __builtin_amdgcn_s_sleep(1);
        }
        __syncthreads();
      }
    }
  }
}

__global__ __launch_bounds__(256) void k_attn(const float* __restrict__ enc, const float* __restrict__ H1,
                       float* __restrict__ ctx){
  __shared__ float h1s[8][HH];
  __shared__ float sc[8][LL];
  __shared__ float part[2][8][LL];
  const int tid = threadIdx.x;
  const int s0 = blockIdx.x*8, b = blockIdx.y;
  for (int i = tid; i < 8*HH; i += 256){
    int si = i >> 10, k = i & 1023;
    h1s[si][k] = H1[(size_t)(s0+si)*BB*HH + (size_t)b*HH + k];
  }
  __syncthreads();
  {
    const int l = tid & 127, half = tid >> 7;
    const float4* er = (const float4*)(enc + ((size_t)l*BB + b)*HH + half*512);
    float a[8];
    #pragma unroll
    for (int s=0;s<8;s++) a[s]=0.f;
    for (int q=0;q<128;q++){
      float4 e = er[q];
      #pragma unroll
      for (int s=0;s<8;s++){
        const float4 h = *(const float4*)(&h1s[s][half*512 + q*4]);
        a[s] += h.x*e.x + h.y*e.y + h.z*e.z + h.w*e.w;
      }
    }
    #pragma unroll
    for (int s=0;s<8;s++) part[half][s][l] = a[s];
  }
  __syncthreads();
  for (int p = tid; p < 1024; p += 256){
    int s = p >> 7, l = p & 127;
    sc[s][l] = (part[0][s][l] + part[1][s][l]) * 0.03125f;
  }
  __syncthreads();
  {
    int s = tid >> 5, lid = tid & 31;
    float v0 = sc[s][lid], v1 = sc[s][lid+32], v2 = sc[s][lid+64], v3 = sc[s][lid+96];
    float m = fmaxf(fmaxf(v0,v1),fmaxf(v2,v3));
    for (int off=16; off>=1; off>>=1) m = fmaxf(m, __shfl_xor(m, off, 32));
    float e0=__expf(v0-m), e1=__expf(v1-m), e2=__expf(v2-m), e3=__expf(v3-m);
    float ssum = e0+e1+e2+e3;
    for (int off=16; off>=1; off>>=1) ssum += __shfl_xor(ssum, off, 32);
    float inv = 1.0f/ssum;
    sc[s][lid]=e0*inv; sc[s][lid+32]=e1*inv; sc[s][lid+64]=e2*inv; sc[s][lid+96]=e3*inv;
  }
  __syncthreads();
  {
    float acc[4][8];
    #pragma unroll
    for (int q=0;q<4;q++)
      #pragma unroll
      for (int s=0;s<8;s++) acc[q][s]=0.f;
    for (int l=0;l<128;l++){
      const float* er = enc + ((size_t)l*BB + b)*HH + tid;
      float a[8];
      #pragma unroll
      for (int s=0;s<8;s++) a[s] = sc[s][l];
      #pragma unroll
      for (int q=0;q<4;q++){
        float e = er[q*256];
        #pragma unroll
        for (int s=0;s<8;s++) acc[q][s] = fmaf(a[s], e, acc[q][s]);
      }
    }
    #pragma unroll
    for (int s=0;s<8;s++)
      #pragma unroll
      for (int q=0;q<4;q++)
        ctx[(size_t)(s0+s)*BB*HH + (size_t)b*HH + tid + q*256] = acc[q][s];
  }
}

__global__ __launch_bounds__(256) void k_logit(const float* __restrict__ H1, const float* __restrict__ ctx,
                        const float* __restrict__ Wout, const float* __restrict__ bout,
                        const int* __restrict__ inp, const int* __restrict__ ts,
                        float* __restrict__ outp, float* __restrict__ bce){
  __shared__ float rbuf[256];
  const int i = blockIdx.x;
  const int b = i >> 7, t = i & 127;
  const int v = inp[b*LL + t];
  const int tid = threadIdx.x;
  const float* h1r = H1 + ((size_t)t*BB + b)*HH;
  const float* cxr = ctx + ((size_t)t*BB + b)*HH;
  float acc = 0.f;
  #pragma unroll
  for (int q=0;q<4;q++){
    int k = tid + q*256;
    acc = fmaf(h1r[k], Wout[(size_t)k*VV + v], acc);
  }
  #pragma unroll
  for (int q=0;q<4;q++){
    int k = tid + q*256;
    acc = fmaf(cxr[k], Wout[(size_t)(k+1024)*VV + v], acc);
  }
  rbuf[tid] = acc;
  __syncthreads();
  for (int s=128; s>0; s>>=1){
    if (tid < s) rbuf[tid] += rbuf[tid+s];
    __syncthreads();
  }
  if (tid==0){
    float logit = rbuf[0] + bout[v];
    float p = 1.0f/(1.0f + expf(-logit));
    outp[b*LL + t] = p;
    float pc = fminf(fmaxf(p, 1e-12f), 1.0f - 1e-7f);
    float tg = (float)ts[0];
    bce[i] = -(tg*logf(pc) + (1.0f-tg)*log1pf(-pc));
  }
}

__global__ void k_loss(const float* __restrict__ bce, float* __restrict__ out0){
  __shared__ float rbuf[256];
  int tid = threadIdx.x;
  float s = 0.f;
  for (int i = tid; i < 2048; i += 256) s += bce[i];
  rbuf[tid] = s; __syncthreads();
  for (int st=128; st>0; st>>=1){
    if (tid<st) rbuf[tid]+=rbuf[tid+st];
    __syncthreads();
  }
  if (tid==0) out0[0] = rbuf[0] * (1.0f/(2048.0f*16.0f));
}

extern "C" void kernel_launch(void* const* d_in, const int* in_sizes, int n_in,
                              void* d_out, int out_size, void* d_ws, size_t ws_size,
                              hipStream_t stream){
  (void)in_sizes; (void)n_in; (void)out_size; (void)ws_size;
  const int*   inp   = (const int*)d_in[0];
  const int*   ts    = (const int*)d_in[2];
  const float* emb   = (const float*)d_in[3];
  const float* encW  = (const float*)d_in[4];
  const float* encb  = (const float*)d_in[5];
  const float* Wih0  = (const float*)d_in[6];
  const float* Whh0  = (const float*)d_in[7];
  const float* bih0  = (const float*)d_in[8];
  const float* bhh0  = (const float*)d_in[9];
  const float* Wih1  = (const float*)d_in[10];
  const float* Whh1  = (const float*)d_in[11];
  const float* bih1  = (const float*)d_in[12];
  const float* bhh1  = (const float*)d_in[13];
  const float* Wout  = (const float*)d_in[14];
  const float* bout  = (const float*)d_in[15];
  float* out = (float*)d_out;

  float* ws      = (float*)d_ws;
  float* enc_out = ws;
  float* H0      = enc_out + 2097152;
  float* H1      = H0 + 2097152;
  float* GX1     = H1 + 2097152;     // unused hole (layout kept stable)
  float* CTX     = GX1 + 6291456;
  float* gx0     = CTX + 2097152;    // unused hole
  float* bceb    = gx0 + 3072;
  int*   rowidx  = (int*)(bceb + 2048);
  int*   flags   = rowidx + 2048;    // 256 flags x 32 ints (128B lines)
  int*   go      = flags + 256*32;   // 1 go word on its own line

  hipMemsetAsync(flags, 0, (256*32 + 32)*sizeof(int), stream);
  k_rowidx<<<8,256,0,stream>>>(inp, rowidx);
  k_gemm<1,512><<<dim3(64,2),256,0,stream>>>(emb, rowidx, encW, encb, enc_out, HH);

  const float* enclast = enc_out + (size_t)127*BB*HH;

  k_chains<<<NBLK,256,0,stream>>>(enclast, H0, H1, Whh0, Whh1, Wih0, Wih1, emb,
                                  bih0, bhh0, bhh1, bih1, flags, go);
  k_attn<<<dim3(16,16),256,0,stream>>>(enc_out, H1, CTX);
  k_logit<<<2048,256,0,stream>>>(H1, CTX, Wout, bout, inp, ts, out+1, bceb);
  k_loss<<<1,256,0,stream>>>(bceb, out);
}

// Round 8
// 2250.672 us; speedup vs baseline: 1.3732x; 1.3732x over previous
//
#include <hip/hip_runtime.h>
#include <math.h>

#define BB 16
#define LL 128
#define HH 1024
#define EE 512
#define VV 32000
#define G3 3072
#define NBLK 256

__device__ __forceinline__ float sigmoidf_(float x){ return 1.0f/(1.0f+expf(-x)); }

__global__ void k_rowidx(const int* __restrict__ inp, int* __restrict__ idx){
  int r = blockIdx.x*256 + threadIdx.x;
  if (r < 2048){ int l = r >> 4, b = r & 15; idx[r] = inp[b*LL + l]; }
}

template<int ACT, int KK>
__global__ __launch_bounds__(256) void k_gemm(const float* __restrict__ A, const int* __restrict__ rowidx,
                       const float* __restrict__ Bm, const float* __restrict__ bias,
                       float* __restrict__ C, int N){
  constexpr int KS = (KK==512)?9:10;
  __shared__ float As[32*KK];
  const int tid = threadIdx.x;
  const int r0 = blockIdx.x*32;
  const int c  = blockIdx.y*512 + (tid<<1);
  for (int i = tid; i < 32*KK; i += 256){
    int rr = i >> KS;
    int row = r0 + rr;
    int arow = rowidx ? rowidx[row] : row;
    int kk = i - (rr<<KS);
    As[i] = A[(size_t)arow*KK + kk];
  }
  __syncthreads();
  float2 acc[32];
  #pragma unroll
  for (int r=0;r<32;r++){ acc[r].x=0.f; acc[r].y=0.f; }
  for (int k=0;k<KK;k++){
    const float2 w = *(const float2*)(Bm + (size_t)k*N + c);
    #pragma unroll
    for (int r=0;r<32;r++){
      float a = As[(r<<KS)+k];
      acc[r].x = fmaf(a,w.x,acc[r].x);
      acc[r].y = fmaf(a,w.y,acc[r].y);
    }
  }
  const float2 bv = *(const float2*)(bias + c);
  #pragma unroll
  for (int r=0;r<32;r++){
    float x = acc[r].x + bv.x, y = acc[r].y + bv.y;
    if (ACT==1){ x = tanhf(x); y = tanhf(y); }
    *(float2*)(C + (size_t)(r0+r)*N + c) = make_float2(x,y);
  }
}

// Fused persistent GRU chains, v2 decomposition:
// lane = kl(0..15) x cg(0..3); thread owns batch b = wave*4+cg, all 12
// gate-cols, k in {kl*4 + 64*i}. Reduction = 4-stage shfl over kl.
// Weight LDS reads broadcast across the 4 cg groups (same address, free).
// Round t: layer0 step t (t<128); gx1 = h0[t-1]@Wih1; layer1 step t-1 (t>=1).
// Aggregator grid barrier (fence-free handshake, write-through h stores).
__global__ __launch_bounds__(256,1) void k_chains(
    const float* enclast, float* H0all, float* H1all,
    const float* __restrict__ Whh0, const float* __restrict__ Whh1,
    const float* __restrict__ Wih0, const float* __restrict__ Wih1,
    const float* __restrict__ emb,
    const float* __restrict__ bih0, const float* __restrict__ bhh0,
    const float* __restrict__ bhh1, const float* __restrict__ bih1,
    int* flags, int* go)
{
  __shared__ float w0l[12][1024];
  __shared__ float w1l[12][1024];
  __shared__ float wil[12][1024];
  const int tid  = threadIdx.x;
  const int lane = tid & 63;
  const int bc   = tid >> 6;
  const int kl   = lane & 15;
  const int cg   = lane >> 4;
  const int jb   = blockIdx.x << 2;
  const int b    = (bc << 2) + cg;     // batch this thread accumulates
  const int jp_  = jb + kl;            // j-col for pointwise lanes (kl<4)
  const bool act = (kl < 4);

  // ---- prologue 1: gx0 for this block's 4 j-cols (w0l as scratch) ----
  float g0r=0.f, g0z=0.f, g0n=0.f;
  {
    for (int idx = tid; idx < 1536; idx += 256){
      int g = idx >> 9, k = idx & 511;
      float4 a = *(const float4*)(Wih0 + (size_t)k*G3 + g*1024 + jb);
      w0l[g*4+0][k]=a.x; w0l[g*4+1][k]=a.y; w0l[g*4+2][k]=a.z; w0l[g*4+3][k]=a.w;
    }
    __syncthreads();
    const float* e1 = emb + EE;   // SOS row (index 1)
    float ag[12];
    #pragma unroll
    for (int c=0;c<12;c++) ag[c]=0.f;
    #pragma unroll
    for (int i=0;i<8;i++){
      float4 e = *(const float4*)(e1 + i*64 + (kl<<2));
      #pragma unroll
      for (int c=0;c<12;c++){
        const float4 w = *(const float4*)(&w0l[c][i*64 + (kl<<2)]);
        float v = ag[c];
        v=fmaf(w.x,e.x,v); v=fmaf(w.y,e.y,v); v=fmaf(w.z,e.z,v); v=fmaf(w.w,e.w,v);
        ag[c]=v;
      }
    }
    #pragma unroll
    for (int c=0;c<12;c++){
      float v = ag[c];
      v+=__shfl_xor(v,1,64); v+=__shfl_xor(v,2,64);
      v+=__shfl_xor(v,4,64); v+=__shfl_xor(v,8,64);
      ag[c]=v;
    }
    if (act){
      float sr=0.f, sz=0.f, sn=0.f;
      #pragma unroll
      for (int jj=0;jj<4;jj++){
        bool sel = (kl==jj);
        sr = sel ? ag[jj]   : sr;
        sz = sel ? ag[4+jj] : sz;
        sn = sel ? ag[8+jj] : sn;
      }
      g0r = sr + bih0[jp_];
      g0z = sz + bih0[1024+jp_];
      g0n = sn + bih0[2048+jp_];
    }
    __syncthreads();   // done with scratch
  }

  // ---- prologue 2: stage the three weight slices ----
  for (int idx = tid; idx < 3072; idx += 256){
    int g = idx >> 10, k = idx & 1023;
    float4 a = *(const float4*)(Whh0 + (size_t)k*G3 + g*1024 + jb);
    w0l[g*4+0][k]=a.x; w0l[g*4+1][k]=a.y; w0l[g*4+2][k]=a.z; w0l[g*4+3][k]=a.w;
    float4 d = *(const float4*)(Whh1 + (size_t)k*G3 + g*1024 + jb);
    w1l[g*4+0][k]=d.x; w1l[g*4+1][k]=d.y; w1l[g*4+2][k]=d.z; w1l[g*4+3][k]=d.w;
    float4 e = *(const float4*)(Wih1 + (size_t)k*G3 + g*1024 + jb);
    wil[g*4+0][k]=e.x; wil[g*4+1][k]=e.y; wil[g*4+2][k]=e.z; wil[g*4+3][k]=e.w;
  }
  float b0r_=0.f,b0z_=0.f,b0n_=0.f,b1r_=0.f,b1z_=0.f,b1n_=0.f,bir_=0.f,biz_=0.f,bin_=0.f;
  if (act){
    b0r_ = bhh0[jp_]; b0z_ = bhh0[1024+jp_]; b0n_ = bhh0[2048+jp_];
    b1r_ = bhh1[jp_]; b1z_ = bhh1[1024+jp_]; b1n_ = bhh1[2048+jp_];
    bir_ = bih1[jp_]; biz_ = bih1[1024+jp_]; bin_ = bih1[2048+jp_];
  }
  __syncthreads();

  for (int t = 0; t <= LL; ++t){
    const float* hp0 = (t==0) ? enclast : (H0all + (size_t)(t-1)*(BB*HH));
    const float* hp1 = (t<=1) ? enclast : (H1all + (size_t)(t-2)*(BB*HH));
    // hoisted scalar prev-h loads (hide L3 latency under the MACs)
    float hprev0 = 0.f, hprev1 = 0.f;
    if (act){
      hprev0 = hp0[(size_t)b*HH + jp_];
      hprev1 = hp1[(size_t)b*HH + jp_];
    }

    // ---- phase A: acc0 = h0prev@Whh0, accg = h0prev@Wih1 ----
    float acc0[12], accg[12];
    #pragma unroll
    for (int c=0;c<12;c++){ acc0[c]=0.f; accg[c]=0.f; }
    {
      const float* hrow = hp0 + (size_t)b*HH;
      for (int i=0;i<16;i++){
        float4 hv = *(const float4*)(hrow + i*64 + (kl<<2));
        #pragma unroll
        for (int c=0;c<12;c++){
          const float4 wa = *(const float4*)(&w0l[c][i*64 + (kl<<2)]);
          float v = acc0[c];
          v=fmaf(wa.x,hv.x,v); v=fmaf(wa.y,hv.y,v); v=fmaf(wa.z,hv.z,v); v=fmaf(wa.w,hv.w,v);
          acc0[c]=v;
          const float4 wg = *(const float4*)(&wil[c][i*64 + (kl<<2)]);
          float u = accg[c];
          u=fmaf(wg.x,hv.x,u); u=fmaf(wg.y,hv.y,u); u=fmaf(wg.z,hv.z,u); u=fmaf(wg.w,hv.w,u);
          accg[c]=u;
        }
      }
    }
    #pragma unroll
    for (int c=0;c<12;c++){
      float v = acc0[c];
      v+=__shfl_xor(v,1,64); v+=__shfl_xor(v,2,64);
      v+=__shfl_xor(v,4,64); v+=__shfl_xor(v,8,64);
      acc0[c]=v;
      float u = accg[c];
      u+=__shfl_xor(u,1,64); u+=__shfl_xor(u,2,64);
      u+=__shfl_xor(u,4,64); u+=__shfl_xor(u,8,64);
      accg[c]=u;
    }

    if (t < LL && act){
      float ghr=0.f, ghz=0.f, ghn=0.f;
      #pragma unroll
      for (int jj=0;jj<4;jj++){
        bool sel = (kl==jj);
        ghr = sel ? acc0[jj]   : ghr;
        ghz = sel ? acc0[4+jj] : ghz;
        ghn = sel ? acc0[8+jj] : ghn;
      }
      float r = sigmoidf_(g0r + ghr + b0r_);
      float z = sigmoidf_(g0z + ghz + b0z_);
      float n = tanhf    (g0n + r*(ghn + b0n_));
      float hnew = (1.f-z)*n + z*hprev0;
      __hip_atomic_store((int*)&H0all[(size_t)t*(BB*HH) + (size_t)b*HH + jp_],
                         __float_as_int(hnew),
                         __ATOMIC_RELAXED, __HIP_MEMORY_SCOPE_AGENT);
    }

    // ---- phase B: acc1 = h1prev@Whh1; layer1 gates with accg ----
    if (t >= 1){
      float acc1[12];
      #pragma unroll
      for (int c=0;c<12;c++) acc1[c]=0.f;
      const float* hrow = hp1 + (size_t)b*HH;
      for (int i=0;i<16;i++){
        float4 hv = *(const float4*)(hrow + i*64 + (kl<<2));
        #pragma unroll
        for (int c=0;c<12;c++){
          const float4 w = *(const float4*)(&w1l[c][i*64 + (kl<<2)]);
          float v = acc1[c];
          v=fmaf(w.x,hv.x,v); v=fmaf(w.y,hv.y,v); v=fmaf(w.z,hv.z,v); v=fmaf(w.w,hv.w,v);
          acc1[c]=v;
        }
      }
      #pragma unroll
      for (int c=0;c<12;c++){
        float v = acc1[c];
        v+=__shfl_xor(v,1,64); v+=__shfl_xor(v,2,64);
        v+=__shfl_xor(v,4,64); v+=__shfl_xor(v,8,64);
        acc1[c]=v;
      }
      if (act){
        float ghr=0.f, ghz=0.f, ghn=0.f, gxr=0.f, gxz=0.f, gxn=0.f;
        #pragma unroll
        for (int jj=0;jj<4;jj++){
          bool sel = (kl==jj);
          ghr = sel ? acc1[jj]   : ghr;
          ghz = sel ? acc1[4+jj] : ghz;
          ghn = sel ? acc1[8+jj] : ghn;
          gxr = sel ? accg[jj]   : gxr;
          gxz = sel ? accg[4+jj] : gxz;
          gxn = sel ? accg[8+jj] : gxn;
        }
        float r = sigmoidf_(gxr + bir_ + ghr + b1r_);
        float z = sigmoidf_(gxz + biz_ + ghz + b1z_);
        float n = tanhf    (gxn + bin_ + r*(ghn + b1n_));
        float hnew = (1.f-z)*n + z*hprev1;
        __hip_atomic_store((int*)&H1all[(size_t)(t-1)*(BB*HH) + (size_t)b*HH + jp_],
                           __float_as_int(hnew),
                           __ATOMIC_RELAXED, __HIP_MEMORY_SCOPE_AGENT);
      }
    }

    // ---- handshake ----
    if (t < LL){
      const int val = t + 1;
      asm volatile("s_waitcnt vmcnt(0)" ::: "memory");
      __syncthreads();
      if (tid == 0)
        __hip_atomic_store(&flags[(int)blockIdx.x*32], val,
                           __ATOMIC_RELAXED, __HIP_MEMORY_SCOPE_AGENT);
      if (blockIdx.x == 0){
        while (__hip_atomic_load(&flags[tid*32], __ATOMIC_RELAXED,
                                 __HIP_MEMORY_SCOPE_AGENT) < val)
          __builtin_amdgcn_s_sleep(1);
        __syncthreads();
        if (tid == 0)
          __hip_atomic_store(go, val, __ATOMIC_RELAXED, __HIP_MEMORY_SCOPE_AGENT);
      } else {
        if (tid == 0){
          while (__hip_atomic_load(go, __ATOMIC_RELAXED,
                                   __HIP_MEMORY_SCOPE_AGENT) < val)
            __builtin_amdgcn_s_sleep(1);
        }
        __syncthreads();
      }
    }
  }
}

__global__ __launch_bounds__(256) void k_attn(const float* __restrict__ enc, const float* __restrict__ H1,
                       float* __restrict__ ctx){
  __shared__ float h1s[8][HH];
  __shared__ float sc[8][LL];
  __shared__ float part[2][8][LL];
  const int tid = threadIdx.x;
  const int s0 = blockIdx.x*8, b = blockIdx.y;
  for (int i = tid; i < 8*HH; i += 256){
    int si = i >> 10, k = i & 1023;
    h1s[si][k] = H1[(size_t)(s0+si)*BB*HH + (size_t)b*HH + k];
  }
  __syncthreads();
  {
    const int l = tid & 127, half = tid >> 7;
    const float4* er = (const float4*)(enc + ((size_t)l*BB + b)*HH + half*512);
    float a[8];
    #pragma unroll
    for (int s=0;s<8;s++) a[s]=0.f;
    for (int q=0;q<128;q++){
      float4 e = er[q];
      #pragma unroll
      for (int s=0;s<8;s++){
        const float4 h = *(const float4*)(&h1s[s][half*512 + q*4]);
        a[s] += h.x*e.x + h.y*e.y + h.z*e.z + h.w*e.w;
      }
    }
    #pragma unroll
    for (int s=0;s<8;s++) part[half][s][l] = a[s];
  }
  __syncthreads();
  for (int p = tid; p < 1024; p += 256){
    int s = p >> 7, l = p & 127;
    sc[s][l] = (part[0][s][l] + part[1][s][l]) * 0.03125f;
  }
  __syncthreads();
  {
    int s = tid >> 5, lid = tid & 31;
    float v0 = sc[s][lid], v1 = sc[s][lid+32], v2 = sc[s][lid+64], v3 = sc[s][lid+96];
    float m = fmaxf(fmaxf(v0,v1),fmaxf(v2,v3));
    for (int off=16; off>=1; off>>=1) m = fmaxf(m, __shfl_xor(m, off, 32));
    float e0=__expf(v0-m), e1=__expf(v1-m), e2=__expf(v2-m), e3=__expf(v3-m);
    float ssum = e0+e1+e2+e3;
    for (int off=16; off>=1; off>>=1) ssum += __shfl_xor(ssum, off, 32);
    float inv = 1.0f/ssum;
    sc[s][lid]=e0*inv; sc[s][lid+32]=e1*inv; sc[s][lid+64]=e2*inv; sc[s][lid+96]=e3*inv;
  }
  __syncthreads();
  {
    float acc[4][8];
    #pragma unroll
    for (int q=0;q<4;q++)
      #pragma unroll
      for (int s=0;s<8;s++) acc[q][s]=0.f;
    for (int l=0;l<128;l++){
      const float* er = enc + ((size_t)l*BB + b)*HH + tid;
      float a[8];
      #pragma unroll
      for (int s=0;s<8;s++) a[s] = sc[s][l];
      #pragma unroll
      for (int q=0;q<4;q++){
        float e = er[q*256];
        #pragma unroll
        for (int s=0;s<8;s++) acc[q][s] = fmaf(a[s], e, acc[q][s]);
      }
    }
    #pragma unroll
    for (int s=0;s<8;s++)
      #pragma unroll
      for (int q=0;q<4;q++)
        ctx[(size_t)(s0+s)*BB*HH + (size_t)b*HH + tid + q*256] = acc[q][s];
  }
}

__global__ __launch_bounds__(256) void k_logit(const float* __restrict__ H1, const float* __restrict__ ctx,
                        const float* __restrict__ Wout, const float* __restrict__ bout,
                        const int* __restrict__ inp, const int* __restrict__ ts,
                        float* __restrict__ outp, float* __restrict__ bce){
  __shared__ float rbuf[256];
  const int i = blockIdx.x;
  const int b = i >> 7, t = i & 127;
  const int v = inp[b*LL + t];
  const int tid = threadIdx.x;
  const float* h1r = H1 + ((size_t)t*BB + b)*HH;
  const float* cxr = ctx + ((size_t)t*BB + b)*HH;
  float acc = 0.f;
  #pragma unroll
  for (int q=0;q<4;q++){
    int k = tid + q*256;
    acc = fmaf(h1r[k], Wout[(size_t)k*VV + v], acc);
  }
  #pragma unroll
  for (int q=0;q<4;q++){
    int k = tid + q*256;
    acc = fmaf(cxr[k], Wout[(size_t)(k+1024)*VV + v], acc);
  }
  rbuf[tid] = acc;
  __syncthreads();
  for (int s=128; s>0; s>>=1){
    if (tid < s) rbuf[tid] += rbuf[tid+s];
    __syncthreads();
  }
  if (tid==0){
    float logit = rbuf[0] + bout[v];
    float p = 1.0f/(1.0f + expf(-logit));
    outp[b*LL + t] = p;
    float pc = fminf(fmaxf(p, 1e-12f), 1.0f - 1e-7f);
    float tg = (float)ts[0];
    bce[i] = -(tg*logf(pc) + (1.0f-tg)*log1pf(-pc));
  }
}

__global__ void k_loss(const float* __restrict__ bce, float* __restrict__ out0){
  __shared__ float rbuf[256];
  int tid = threadIdx.x;
  float s = 0.f;
  for (int i = tid; i < 2048; i += 256) s += bce[i];
  rbuf[tid] = s; __syncthreads();
  for (int st=128; st>0; st>>=1){
    if (tid<st) rbuf[tid]+=rbuf[tid+st];
    __syncthreads();
  }
  if (tid==0) out0[0] = rbuf[0] * (1.0f/(2048.0f*16.0f));
}

extern "C" void kernel_launch(void* const* d_in, const int* in_sizes, int n_in,
                              void* d_out, int out_size, void* d_ws, size_t ws_size,
                              hipStream_t stream){
  (void)in_sizes; (void)n_in; (void)out_size; (void)ws_size;
  const int*   inp   = (const int*)d_in[0];
  const int*   ts    = (const int*)d_in[2];
  const float* emb   = (const float*)d_in[3];
  const float* encW  = (const float*)d_in[4];
  const float* encb  = (const float*)d_in[5];
  const float* Wih0  = (const float*)d_in[6];
  const float* Whh0  = (const float*)d_in[7];
  const float* bih0  = (const float*)d_in[8];
  const float* bhh0  = (const float*)d_in[9];
  const float* Wih1  = (const float*)d_in[10];
  const float* Whh1  = (const float*)d_in[11];
  const float* bih1  = (const float*)d_in[12];
  const float* bhh1  = (const float*)d_in[13];
  const float* Wout  = (const float*)d_in[14];
  const float* bout  = (const float*)d_in[15];
  float* out = (float*)d_out;

  float* ws      = (float*)d_ws;
  float* enc_out = ws;
  float* H0      = enc_out + 2097152;
  float* H1      = H0 + 2097152;
  float* GX1     = H1 + 2097152;     // unused hole (layout kept stable)
  float* CTX     = GX1 + 6291456;
  float* gx0     = CTX + 2097152;    // unused hole
  float* bceb    = gx0 + 3072;
  int*   rowidx  = (int*)(bceb + 2048);
  int*   flags   = rowidx + 2048;    // 256 flags x 32 ints (128B lines)
  int*   go      = flags + 256*32;   // 1 go word on its own line

  hipMemsetAsync(flags, 0, (256*32 + 32)*sizeof(int), stream);
  k_rowidx<<<8,256,0,stream>>>(inp, rowidx);
  k_gemm<1,512><<<dim3(64,2),256,0,stream>>>(emb, rowidx, encW, encb, enc_out, HH);

  const float* enclast = enc_out + (size_t)127*BB*HH;

  k_chains<<<NBLK,256,0,stream>>>(enclast, H0, H1, Whh0, Whh1, Wih0, Wih1, emb,
                                  bih0, bhh0, bhh1, bih1, flags, go);
  k_attn<<<dim3(16,16),256,0,stream>>>(enc_out, H1, CTX);
  k_logit<<<2048,256,0,stream>>>(H1, CTX, Wout, bout, inp, ts, out+1, bceb);
  k_loss<<<1,256,0,stream>>>(bceb, out);
}

// Round 9
// 2078.838 us; speedup vs baseline: 1.4867x; 1.0827x over previous
//
#include <hip/hip_runtime.h>
#include <math.h>

#define BB 16
#define LL 128
#define HH 1024
#define EE 512
#define VV 32000
#define G3 3072
#define NBLK 256

__device__ __forceinline__ float sigmoidf_(float x){ return 1.0f/(1.0f+expf(-x)); }

// 5-stage butterfly over kl (lanes 0..31 within each 32-half of a wave)
__device__ __forceinline__ float redk(float v){
  v += __shfl_xor(v, 1, 64); v += __shfl_xor(v, 2, 64);
  v += __shfl_xor(v, 4, 64); v += __shfl_xor(v, 8, 64);
  v += __shfl_xor(v, 16, 64);
  return v;
}

__global__ void k_rowidx(const int* __restrict__ inp, int* __restrict__ idx){
  int r = blockIdx.x*256 + threadIdx.x;
  if (r < 2048){ int l = r >> 4, b = r & 15; idx[r] = inp[b*LL + l]; }
}

template<int ACT, int KK>
__global__ __launch_bounds__(256) void k_gemm(const float* __restrict__ A, const int* __restrict__ rowidx,
                       const float* __restrict__ Bm, const float* __restrict__ bias,
                       float* __restrict__ C, int N){
  constexpr int KS = (KK==512)?9:10;
  __shared__ float As[32*KK];
  const int tid = threadIdx.x;
  const int r0 = blockIdx.x*32;
  const int c  = blockIdx.y*512 + (tid<<1);
  for (int i = tid; i < 32*KK; i += 256){
    int rr = i >> KS;
    int row = r0 + rr;
    int arow = rowidx ? rowidx[row] : row;
    int kk = i - (rr<<KS);
    As[i] = A[(size_t)arow*KK + kk];
  }
  __syncthreads();
  float2 acc[32];
  #pragma unroll
  for (int r=0;r<32;r++){ acc[r].x=0.f; acc[r].y=0.f; }
  for (int k=0;k<KK;k++){
    const float2 w = *(const float2*)(Bm + (size_t)k*N + c);
    #pragma unroll
    for (int r=0;r<32;r++){
      float a = As[(r<<KS)+k];
      acc[r].x = fmaf(a,w.x,acc[r].x);
      acc[r].y = fmaf(a,w.y,acc[r].y);
    }
  }
  const float2 bv = *(const float2*)(bias + c);
  #pragma unroll
  for (int r=0;r<32;r++){
    float x = acc[r].x + bv.x, y = acc[r].y + bv.y;
    if (ACT==1){ x = tanhf(x); y = tanhf(y); }
    *(float2*)(C + (size_t)(r0+r)*N + c) = make_float2(x,y);
  }
}

// Fused persistent GRU chains v3: 512 threads (2 waves/SIMD), dual-chain
// overlapped barrier with layer-1 lagging 2 steps.
// Round t (t=0..129):
//   wB(t): wait all flagsB >= t        (guards H0[t-2], H1[t-3] reads)
//   B(t):  [t>=2] gx1 = h0[t-2]@Wih1; layer1 step t-2 (reads H1[t-3]); store h1[t-2]
//   sB(t): vmcnt(0); sync; flagB = t+1
//   wA(t): wait all flagsA >= t        (guards H0[t-1] read)
//   A(t):  [t<=127] layer0 step t; store h0[t]
//   sA(t): vmcnt(0); sync; flagA = t+1
// Thread org: wave wv(0..7), half bh(0..1) -> batch b=wv*2+bh; kl(0..31) covers
// k in {kl*4+128i}. Reduction = 5-stage shfl. Weight LDS reads 2-way broadcast.
__global__ __launch_bounds__(512,1) void k_chains(
    const float* enclast, float* H0all, float* H1all,
    const float* __restrict__ Whh0, const float* __restrict__ Whh1,
    const float* __restrict__ Wih0, const float* __restrict__ Wih1,
    const float* __restrict__ emb,
    const float* __restrict__ bih0, const float* __restrict__ bhh0,
    const float* __restrict__ bhh1, const float* __restrict__ bih1,
    int* flagsB, int* flagsA)
{
  __shared__ float w0l[12][1024];   // Whh0 cols
  __shared__ float w1l[12][1024];   // Whh1 cols
  __shared__ float wil[12][1024];   // Wih1 cols
  const int tid  = threadIdx.x;
  const int lane = tid & 63;
  const int wv   = tid >> 6;        // 0..7
  const int kl   = lane & 31;
  const int bh   = lane >> 5;       // 0..1
  const int jb   = blockIdx.x << 2;
  const int b    = (wv << 1) + bh;  // batch this thread accumulates
  const int jp_  = jb + kl;         // j-col for pointwise lanes (kl<4)
  const bool act = (kl < 4);
  const int koff = kl << 2;

  // ---- prologue 1: gx0 for this block's 4 j-cols (w0l as scratch) ----
  float g0r=0.f, g0z=0.f, g0n=0.f;
  {
    for (int idx = tid; idx < 1536; idx += 512){
      int g = idx >> 9, k = idx & 511;
      float4 a = *(const float4*)(Wih0 + (size_t)k*G3 + g*1024 + jb);
      w0l[g*4+0][k]=a.x; w0l[g*4+1][k]=a.y; w0l[g*4+2][k]=a.z; w0l[g*4+3][k]=a.w;
    }
    __syncthreads();
    const float* e1 = emb + EE;   // SOS row (index 1)
    float ag[12];
    #pragma unroll
    for (int c=0;c<12;c++) ag[c]=0.f;
    #pragma unroll
    for (int i=0;i<4;i++){
      float4 e = *(const float4*)(e1 + i*128 + koff);
      #pragma unroll
      for (int c=0;c<12;c++){
        const float4 w = *(const float4*)(&w0l[c][i*128 + koff]);
        float v = ag[c];
        v=fmaf(w.x,e.x,v); v=fmaf(w.y,e.y,v); v=fmaf(w.z,e.z,v); v=fmaf(w.w,e.w,v);
        ag[c]=v;
      }
    }
    #pragma unroll
    for (int c=0;c<12;c++) ag[c] = redk(ag[c]);
    if (act){
      float sr=0.f, sz=0.f, sn=0.f;
      #pragma unroll
      for (int jj=0;jj<4;jj++){
        bool sel = (kl==jj);
        sr = sel ? ag[jj]   : sr;
        sz = sel ? ag[4+jj] : sz;
        sn = sel ? ag[8+jj] : sn;
      }
      g0r = sr + bih0[jp_];
      g0z = sz + bih0[1024+jp_];
      g0n = sn + bih0[2048+jp_];
    }
    __syncthreads();   // done with scratch
  }

  // ---- prologue 2: stage the three weight slices ----
  for (int idx = tid; idx < 3072; idx += 512){
    int g = idx >> 10, k = idx & 1023;
    float4 a = *(const float4*)(Whh0 + (size_t)k*G3 + g*1024 + jb);
    w0l[g*4+0][k]=a.x; w0l[g*4+1][k]=a.y; w0l[g*4+2][k]=a.z; w0l[g*4+3][k]=a.w;
    float4 d = *(const float4*)(Whh1 + (size_t)k*G3 + g*1024 + jb);
    w1l[g*4+0][k]=d.x; w1l[g*4+1][k]=d.y; w1l[g*4+2][k]=d.z; w1l[g*4+3][k]=d.w;
    float4 e = *(const float4*)(Wih1 + (size_t)k*G3 + g*1024 + jb);
    wil[g*4+0][k]=e.x; wil[g*4+1][k]=e.y; wil[g*4+2][k]=e.z; wil[g*4+3][k]=e.w;
  }
  float b0r_=0.f,b0z_=0.f,b0n_=0.f,b1r_=0.f,b1z_=0.f,b1n_=0.f,bir_=0.f,biz_=0.f,bin_=0.f;
  if (act){
    b0r_ = bhh0[jp_]; b0z_ = bhh0[1024+jp_]; b0n_ = bhh0[2048+jp_];
    b1r_ = bhh1[jp_]; b1z_ = bhh1[1024+jp_]; b1n_ = bhh1[2048+jp_];
    bir_ = bih1[jp_]; biz_ = bih1[1024+jp_]; bin_ = bih1[2048+jp_];
  }
  __syncthreads();

  const int myflag = (int)blockIdx.x * 32;
  const int pollfl = (tid & 255) * 32;

  for (int t = 0; t <= LL+1; ++t){
    // ---- wB(t): chain-B wait ----
    if (t >= 1){
      while (__hip_atomic_load(&flagsB[pollfl], __ATOMIC_RELAXED,
                               __HIP_MEMORY_SCOPE_AGENT) < t)
        __builtin_amdgcn_s_sleep(1);
      __syncthreads();
    }

    // ---- B(t): gx1 + layer1 step t-2 ----
    if (t >= 2){
      const float* h0row = H0all + (size_t)(t-2)*(BB*HH) + (size_t)b*HH;
      const float* h1row = ((t==2) ? enclast : (H1all + (size_t)(t-3)*(BB*HH)))
                           + (size_t)b*HH;
      float hprev1 = 0.f;
      if (act) hprev1 = h1row[kl];   // j = jb+kl, but row base needs jp_: fixed below
      // (correct scalar: h1row[jp_ - jb + ... ] -> h1row[jp_] is wrong since
      //  h1row already includes b*HH only; col index is jp_)
      if (act) hprev1 = h1row[jp_];
      float accg[12], acc1[12];
      #pragma unroll
      for (int c=0;c<12;c++){ accg[c]=0.f; acc1[c]=0.f; }
      #pragma unroll
      for (int i=0;i<8;i++){
        float4 h0v = *(const float4*)(h0row + i*128 + koff);
        float4 h1v = *(const float4*)(h1row + i*128 + koff);
        #pragma unroll
        for (int c=0;c<12;c++){
          const float4 wg = *(const float4*)(&wil[c][i*128 + koff]);
          float u = accg[c];
          u=fmaf(wg.x,h0v.x,u); u=fmaf(wg.y,h0v.y,u); u=fmaf(wg.z,h0v.z,u); u=fmaf(wg.w,h0v.w,u);
          accg[c]=u;
          const float4 w1 = *(const float4*)(&w1l[c][i*128 + koff]);
          float v = acc1[c];
          v=fmaf(w1.x,h1v.x,v); v=fmaf(w1.y,h1v.y,v); v=fmaf(w1.z,h1v.z,v); v=fmaf(w1.w,h1v.w,v);
          acc1[c]=v;
        }
      }
      #pragma unroll
      for (int c=0;c<12;c++){ accg[c] = redk(accg[c]); acc1[c] = redk(acc1[c]); }
      if (act){
        float ghr=0.f, ghz=0.f, ghn=0.f, gxr=0.f, gxz=0.f, gxn=0.f;
        #pragma unroll
        for (int jj=0;jj<4;jj++){
          bool sel = (kl==jj);
          ghr = sel ? acc1[jj]   : ghr;
          ghz = sel ? acc1[4+jj] : ghz;
          ghn = sel ? acc1[8+jj] : ghn;
          gxr = sel ? accg[jj]   : gxr;
          gxz = sel ? accg[4+jj] : gxz;
          gxn = sel ? accg[8+jj] : gxn;
        }
        float r = sigmoidf_(gxr + bir_ + ghr + b1r_);
        float z = sigmoidf_(gxz + biz_ + ghz + b1z_);
        float n = tanhf    (gxn + bin_ + r*(ghn + b1n_));
        float hnew = (1.f-z)*n + z*hprev1;
        __hip_atomic_store((int*)&H1all[(size_t)(t-2)*(BB*HH) + (size_t)b*HH + jp_],
                           __float_as_int(hnew),
                           __ATOMIC_RELAXED, __HIP_MEMORY_SCOPE_AGENT);
      }
    }

    // ---- sB(t) ----
    asm volatile("s_waitcnt vmcnt(0)" ::: "memory");
    __syncthreads();
    if (tid == 0)
      __hip_atomic_store(&flagsB[myflag], t+1,
                         __ATOMIC_RELAXED, __HIP_MEMORY_SCOPE_AGENT);

    // ---- wA(t): chain-A wait ----
    if (t >= 1){
      while (__hip_atomic_load(&flagsA[pollfl], __ATOMIC_RELAXED,
                               __HIP_MEMORY_SCOPE_AGENT) < t)
        __builtin_amdgcn_s_sleep(1);
      __syncthreads();
    }

    // ---- A(t): layer0 step t ----
    if (t < LL){
      const float* h0row = ((t==0) ? enclast : (H0all + (size_t)(t-1)*(BB*HH)))
                           + (size_t)b*HH;
      float hprev0 = 0.f;
      if (act) hprev0 = h0row[jp_];
      float acc0[12];
      #pragma unroll
      for (int c=0;c<12;c++) acc0[c]=0.f;
      #pragma unroll
      for (int i=0;i<8;i++){
        float4 hv = *(const float4*)(h0row + i*128 + koff);
        #pragma unroll
        for (int c=0;c<12;c++){
          const float4 w = *(const float4*)(&w0l[c][i*128 + koff]);
          float v = acc0[c];
          v=fmaf(w.x,hv.x,v); v=fmaf(w.y,hv.y,v); v=fmaf(w.z,hv.z,v); v=fmaf(w.w,hv.w,v);
          acc0[c]=v;
        }
      }
      #pragma unroll
      for (int c=0;c<12;c++) acc0[c] = redk(acc0[c]);
      if (act){
        float ghr=0.f, ghz=0.f, ghn=0.f;
        #pragma unroll
        for (int jj=0;jj<4;jj++){
          bool sel = (kl==jj);
          ghr = sel ? acc0[jj]   : ghr;
          ghz = sel ? acc0[4+jj] : ghz;
          ghn = sel ? acc0[8+jj] : ghn;
        }
        float r = sigmoidf_(g0r + ghr + b0r_);
        float z = sigmoidf_(g0z + ghz + b0z_);
        float n = tanhf    (g0n + r*(ghn + b0n_));
        float hnew = (1.f-z)*n + z*hprev0;
        __hip_atomic_store((int*)&H0all[(size_t)t*(BB*HH) + (size_t)b*HH + jp_],
                           __float_as_int(hnew),
                           __ATOMIC_RELAXED, __HIP_MEMORY_SCOPE_AGENT);
      }
    }

    // ---- sA(t) ----
    asm volatile("s_waitcnt vmcnt(0)" ::: "memory");
    __syncthreads();
    if (tid == 0)
      __hip_atomic_store(&flagsA[myflag], t+1,
                         __ATOMIC_RELAXED, __HIP_MEMORY_SCOPE_AGENT);
  }
}

__global__ __launch_bounds__(256) void k_attn(const float* __restrict__ enc, const float* __restrict__ H1,
                       float* __restrict__ ctx){
  __shared__ float h1s[8][HH];
  __shared__ float sc[8][LL];
  __shared__ float part[2][8][LL];
  const int tid = threadIdx.x;
  const int s0 = blockIdx.x*8, b = blockIdx.y;
  for (int i = tid; i < 8*HH; i += 256){
    int si = i >> 10, k = i & 1023;
    h1s[si][k] = H1[(size_t)(s0+si)*BB*HH + (size_t)b*HH + k];
  }
  __syncthreads();
  {
    const int l = tid & 127, half = tid >> 7;
    const float4* er = (const float4*)(enc + ((size_t)l*BB + b)*HH + half*512);
    float a[8];
    #pragma unroll
    for (int s=0;s<8;s++) a[s]=0.f;
    for (int q=0;q<128;q++){
      float4 e = er[q];
      #pragma unroll
      for (int s=0;s<8;s++){
        const float4 h = *(const float4*)(&h1s[s][half*512 + q*4]);
        a[s] += h.x*e.x + h.y*e.y + h.z*e.z + h.w*e.w;
      }
    }
    #pragma unroll
    for (int s=0;s<8;s++) part[half][s][l] = a[s];
  }
  __syncthreads();
  for (int p = tid; p < 1024; p += 256){
    int s = p >> 7, l = p & 127;
    sc[s][l] = (part[0][s][l] + part[1][s][l]) * 0.03125f;
  }
  __syncthreads();
  {
    int s = tid >> 5, lid = tid & 31;
    float v0 = sc[s][lid], v1 = sc[s][lid+32], v2 = sc[s][lid+64], v3 = sc[s][lid+96];
    float m = fmaxf(fmaxf(v0,v1),fmaxf(v2,v3));
    for (int off=16; off>=1; off>>=1) m = fmaxf(m, __shfl_xor(m, off, 32));
    float e0=__expf(v0-m), e1=__expf(v1-m), e2=__expf(v2-m), e3=__expf(v3-m);
    float ssum = e0+e1+e2+e3;
    for (int off=16; off>=1; off>>=1) ssum += __shfl_xor(ssum, off, 32);
    float inv = 1.0f/ssum;
    sc[s][lid]=e0*inv; sc[s][lid+32]=e1*inv; sc[s][lid+64]=e2*inv; sc[s][lid+96]=e3*inv;
  }
  __syncthreads();
  {
    float acc[4][8];
    #pragma unroll
    for (int q=0;q<4;q++)
      #pragma unroll
      for (int s=0;s<8;s++) acc[q][s]=0.f;
    for (int l=0;l<128;l++){
      const float* er = enc + ((size_t)l*BB + b)*HH + tid;
      float a[8];
      #pragma unroll
      for (int s=0;s<8;s++) a[s] = sc[s][l];
      #pragma unroll
      for (int q=0;q<4;q++){
        float e = er[q*256];
        #pragma unroll
        for (int s=0;s<8;s++) acc[q][s] = fmaf(a[s], e, acc[q][s]);
      }
    }
    #pragma unroll
    for (int s=0;s<8;s++)
      #pragma unroll
      for (int q=0;q<4;q++)
        ctx[(size_t)(s0+s)*BB*HH + (size_t)b*HH + tid + q*256] = acc[q][s];
  }
}

__global__ __launch_bounds__(256) void k_logit(const float* __restrict__ H1, const float* __restrict__ ctx,
                        const float* __restrict__ Wout, const float* __restrict__ bout,
                        const int* __restrict__ inp, const int* __restrict__ ts,
                        float* __restrict__ outp, float* __restrict__ bce){
  __shared__ float rbuf[256];
  const int i = blockIdx.x;
  const int b = i >> 7, t = i & 127;
  const int v = inp[b*LL + t];
  const int tid = threadIdx.x;
  const float* h1r = H1 + ((size_t)t*BB + b)*HH;
  const float* cxr = ctx + ((size_t)t*BB + b)*HH;
  float acc = 0.f;
  #pragma unroll
  for (int q=0;q<4;q++){
    int k = tid + q*256;
    acc = fmaf(h1r[k], Wout[(size_t)k*VV + v], acc);
  }
  #pragma unroll
  for (int q=0;q<4;q++){
    int k = tid + q*256;
    acc = fmaf(cxr[k], Wout[(size_t)(k+1024)*VV + v], acc);
  }
  rbuf[tid] = acc;
  __syncthreads();
  for (int s=128; s>0; s>>=1){
    if (tid < s) rbuf[tid] += rbuf[tid+s];
    __syncthreads();
  }
  if (tid==0){
    float logit = rbuf[0] + bout[v];
    float p = 1.0f/(1.0f + expf(-logit));
    outp[b*LL + t] = p;
    float pc = fminf(fmaxf(p, 1e-12f), 1.0f - 1e-7f);
    float tg = (float)ts[0];
    bce[i] = -(tg*logf(pc) + (1.0f-tg)*log1pf(-pc));
  }
}

__global__ void k_loss(const float* __restrict__ bce, float* __restrict__ out0){
  __shared__ float rbuf[256];
  int tid = threadIdx.x;
  float s = 0.f;
  for (int i = tid; i < 2048; i += 256) s += bce[i];
  rbuf[tid] = s; __syncthreads();
  for (int st=128; st>0; st>>=1){
    if (tid<st) rbuf[tid]+=rbuf[tid+st];
    __syncthreads();
  }
  if (tid==0) out0[0] = rbuf[0] * (1.0f/(2048.0f*16.0f));
}

extern "C" void kernel_launch(void* const* d_in, const int* in_sizes, int n_in,
                              void* d_out, int out_size, void* d_ws, size_t ws_size,
                              hipStream_t stream){
  (void)in_sizes; (void)n_in; (void)out_size; (void)ws_size;
  const int*   inp   = (const int*)d_in[0];
  const int*   ts    = (const int*)d_in[2];
  const float* emb   = (const float*)d_in[3];
  const float* encW  = (const float*)d_in[4];
  const float* encb  = (const float*)d_in[5];
  const float* Wih0  = (const float*)d_in[6];
  const float* Whh0  = (const float*)d_in[7];
  const float* bih0  = (const float*)d_in[8];
  const float* bhh0  = (const float*)d_in[9];
  const float* Wih1  = (const float*)d_in[10];
  const float* Whh1  = (const float*)d_in[11];
  const float* bih1  = (const float*)d_in[12];
  const float* bhh1  = (const float*)d_in[13];
  const float* Wout  = (const float*)d_in[14];
  const float* bout  = (const float*)d_in[15];
  float* out = (float*)d_out;

  float* ws      = (float*)d_ws;
  float* enc_out = ws;
  float* H0      = enc_out + 2097152;
  float* H1      = H0 + 2097152;
  float* GX1     = H1 + 2097152;     // unused hole (layout kept stable)
  float* CTX     = GX1 + 6291456;
  float* gx0     = CTX + 2097152;    // unused hole
  float* bceb    = gx0 + 3072;
  int*   rowidx  = (int*)(bceb + 2048);
  int*   flagsB  = rowidx + 2048;    // 256 lines x 32 ints
  int*   flagsA  = flagsB + 256*32;  // 256 lines x 32 ints

  hipMemsetAsync(flagsB, 0, 512*32*sizeof(int), stream);
  k_rowidx<<<8,256,0,stream>>>(inp, rowidx);
  k_gemm<1,512><<<dim3(64,2),256,0,stream>>>(emb, rowidx, encW, encb, enc_out, HH);

  const float* enclast = enc_out + (size_t)127*BB*HH;

  k_chains<<<NBLK,512,0,stream>>>(enclast, H0, H1, Whh0, Whh1, Wih0, Wih1, emb,
                                  bih0, bhh0, bhh1, bih1, flagsB, flagsA);
  k_attn<<<dim3(16,16),256,0,stream>>>(enc_out, H1, CTX);
  k_logit<<<2048,256,0,stream>>>(H1, CTX, Wout, bout, inp, ts, out+1, bceb);
  k_loss<<<1,256,0,stream>>>(bceb, out);
}